// Round 1
// 210.802 us; speedup vs baseline: 1.0812x; 1.0812x over previous
//
#include <hip/hip_runtime.h>
#include <hip/hip_bf16.h>

typedef __bf16 bf16x4 __attribute__((ext_vector_type(4)));
typedef __bf16 bf16x8 __attribute__((ext_vector_type(8)));
typedef float  f32x4  __attribute__((ext_vector_type(4)));
typedef float  f32x16 __attribute__((ext_vector_type(16)));

#define MFMA32(a,b,c) __builtin_amdgcn_mfma_f32_32x32x16_bf16((a),(b),(c),0,0,0)

// lgkm-only workgroup barrier: does NOT drain vmcnt, so y-stores and x-prefetch
// loads stay in flight across it. Each wave drains its own LDS ops (lgkmcnt(0))
// before the barrier => producer/consumer LDS ordering is preserved exactly as
// with __syncthreads(), minus the vmcnt(0) store-drain serialization.
#define BAR_LDS() asm volatile("s_waitcnt lgkmcnt(0)\n\ts_barrier" ::: "memory")

// Merged-weight TT forward.
//   W01[m0][(m1*8+r2)][(n0*8+n1)] = sum_r1 c0[m0][r1*4+n0] * c1[(r1*8+m1)][(r2*8+n1)]
//   W23[(m2*8+m3)][(n2*32+n3*8+r2)] = sum_r3 c2[(r2*8+m2)][(r3*8+n2)] * c3[(r3*8+m3)][n3]
// Per 2-batch iter: Xt[col=(b^,n2n3)][k=(n0,n1)] in LDS; per m0-quad:
//   stage A: H[(m1 r2)][(n2n3)] = W01^(m0) @ Xt -> Hb[cl=(b^,m0^,m1)][k=(n2,n3,r2)]
//   stage B (operand-SWAPPED): D[cl][m2m3] = Hb @ W23^T, K=256.
//     A-frag and B-frag lane layouts are identical (A[m=lane&31][k=(lane>>5)*8+j]
//     == B[k=(lane>>5)*8+j][n=lane&31]), so swapping MFMA args leaves all LDS
//     read patterns untouched; output cols become the contiguous m2m3 feature
//     axis -> epilogue stores are fully lane-coalesced (2x128B per instruction).
// 32x32x16 layouts (HW-validated in R1): D[row=(reg&3)+8*(reg>>2)+4*(lane>>5)][col=lane&31].

__global__ __launch_bounds__(256) void tt_kernel(
    const float* __restrict__ x,  const float* __restrict__ c0,
    const float* __restrict__ c1, const float* __restrict__ c2,
    const float* __restrict__ c3, const float* __restrict__ bias,
    float* __restrict__ y)
{
    __shared__ __align__(16) __bf16 w23l[16384];  // 32 KB, A-frag swizzled
    __shared__ __align__(16) __bf16 xt[2048];     //  4 KB
    __shared__ __align__(16) __bf16 hb[16384];    // 32 KB

    const int tid  = threadIdx.x;
    const int wid  = tid >> 6;
    const int lane = tid & 63;
    const int hh   = lane >> 5;   // MFMA k-half
    const int c32  = lane & 31;   // MFMA row/col id
    const int rt   = wid & 1;     // row-tile role
    const int ct   = wid >> 1;    // batch role b^

    // ---- one-time: W23 -> LDS (swizzled: phys_oct = (k>>3) ^ (row&31)) ----
    {
      const int r = tid >> 2, kb = (tid & 3) * 64;
      const int m2 = r >> 3, m3 = r & 7;
      float c3v[8][4];
      #pragma unroll
      for (int r3 = 0; r3 < 8; ++r3)
        #pragma unroll
        for (int n3 = 0; n3 < 4; ++n3)
          c3v[r3][n3] = c3[(r3 * 8 + m3) * 4 + n3];
      for (int j = 0; j < 64; ++j) {
        const int k = kb + j;
        const int n2 = k >> 5, n3 = (k >> 3) & 3, r2 = k & 7;
        float s = 0.f;
        #pragma unroll
        for (int r3 = 0; r3 < 8; ++r3)
          s += c2[(r2 * 8 + m2) * 64 + r3 * 8 + n2] * c3v[r3][n3];
        w23l[r * 256 + (((k >> 3) ^ (r & 31)) << 3) + (k & 7)] = (__bf16)s;
      }
    }

    // ---- one-time: W01 A-frags in registers (wave holds its rt slice) ----
    bf16x8 w01f[8][2];
    {
      const int row = rt * 32 + c32, m1 = row >> 3, r2w = row & 7;
      float c1row[8][8];
      #pragma unroll
      for (int r1 = 0; r1 < 8; ++r1)
        #pragma unroll
        for (int n1 = 0; n1 < 8; ++n1)
          c1row[r1][n1] = c1[(r1 * 8 + m1) * 64 + r2w * 8 + n1];
      for (int m0 = 0; m0 < 8; ++m0) {
        #pragma unroll
        for (int kt = 0; kt < 2; ++kt) {
          const int n0 = kt * 2 + hh;
          #pragma unroll
          for (int j = 0; j < 8; ++j) {
            float s = 0.f;
            #pragma unroll
            for (int r1 = 0; r1 < 8; ++r1)
              s += c0[m0 * 32 + r1 * 4 + n0] * c1row[r1][j];
            w01f[m0][kt][j] = (__bf16)s;
          }
        }
      }
    }

    // ---- one-time: bias regs; feature = q*2048 + p*512 + (hh*4+i)*64 + rt*32 + c32
    float bv[2][4][4];
    #pragma unroll
    for (int q = 0; q < 2; ++q)
      #pragma unroll
      for (int p = 0; p < 4; ++p)
        #pragma unroll
        for (int i = 0; i < 4; ++i)
          bv[q][p][i] = bias[q * 2048 + p * 512 + (hh * 4 + i) * 64 + rt * 32 + c32];

    // ---- x staging geometry (per thread) ----
    const int bsel = tid >> 7, xcol = tid & 31, k0q = (tid >> 5) & 3;
    const int xtoff = (bsel * 32 + xcol) * 32 + ((k0q ^ (xcol & 3)) << 3);

    float xv[8];
    // prologue: stage x for it=0
    {
      const float* xp = x + (size_t)(blockIdx.x * 16 + bsel) * 1024 + xcol;
      #pragma unroll
      for (int j = 0; j < 8; ++j) xv[j] = xp[(k0q * 8 + j) * 32];
      bf16x8 v;
      #pragma unroll
      for (int j = 0; j < 8; ++j) v[j] = (__bf16)xv[j];
      *(bf16x8*)&xt[xtoff] = v;
    }
    BAR_LDS();

    for (int it = 0; it < 8; ++it) {
      const int b0 = (blockIdx.x * 8 + it) * 2;

      // stage-A B-frags (same for both quads)
      bf16x8 xf[2];
      #pragma unroll
      for (int kt = 0; kt < 2; ++kt)
        xf[kt] = *(const bf16x8*)
          &xt[(ct * 32 + c32) * 32 + (((kt * 2 + hh) ^ (c32 & 3)) << 3)];

      #pragma unroll
      for (int q = 0; q < 2; ++q) {
        if (q == 0) {
          // prefetch next pair's x into regs; latency hides under stage B q0 +
          // stage A q1. Wraps on last iter (harmless L3-hit reload).
          const int itn = (it + 1) & 7;
          const float* xp = x + (size_t)((blockIdx.x * 8 + itn) * 2 + bsel) * 1024 + xcol;
          #pragma unroll
          for (int j = 0; j < 8; ++j) xv[j] = xp[(k0q * 8 + j) * 32];
        }

        // ---- stage A: 4 m0 x (32x32, K=32) ----
        #pragma unroll
        for (int m0h = 0; m0h < 4; ++m0h) {
          f32x16 acc = {};
          acc = MFMA32(w01f[q * 4 + m0h][0], xf[0], acc);
          acc = MFMA32(w01f[q * 4 + m0h][1], xf[1], acc);
          #pragma unroll
          for (int p = 0; p < 4; ++p) {
            bf16x4 o;
            #pragma unroll
            for (int i = 0; i < 4; ++i) o[i] = (__bf16)acc[p * 4 + i];
            const int cl = ct * 32 + m0h * 8 + rt * 4 + p;
            *(bf16x4*)&hb[cl * 256 + ((c32 ^ (cl & 31)) << 3) + hh * 4] = o;
          }
        }
        BAR_LDS();

        // ---- stage B: (32x32, K=256), operands swapped, 2 accumulators ----
        const __bf16* arow = &w23l[(rt * 32 + c32) * 256];
        const __bf16* brow = &hb[(ct * 32 + c32) * 256];
        f32x16 acc2a = {}, acc2b = {};
        #pragma unroll
        for (int kt = 0; kt < 16; kt += 2) {
          const int op0 = ((kt * 2 + hh) ^ c32) << 3;
          const int op1 = ((kt * 2 + 2 + hh) ^ c32) << 3;
          acc2a = MFMA32(*(const bf16x8*)&brow[op0], *(const bf16x8*)&arow[op0], acc2a);
          acc2b = MFMA32(*(const bf16x8*)&brow[op1], *(const bf16x8*)&arow[op1], acc2b);
        }

        if (q == 1) {
          // stage xt for it+1: all xf readers passed the q0 barrier long ago;
          // trailing BAR_LDS publishes it for the next iteration.
          bf16x8 v;
          #pragma unroll
          for (int j = 0; j < 8; ++j) v[j] = (__bf16)xv[j];
          *(bf16x8*)&xt[xtoff] = v;
        }

        // ---- epilogue: D[row=8p+4hh+i -> (b=ct, m0h=p, m1=4hh+i)]
        //               [col=rt*32+c32 -> m2m3] ; stores lane-contiguous
        {
          const size_t ybase = (size_t)(b0 + ct) * 4096 + q * 2048 + rt * 32 + c32;
          #pragma unroll
          for (int p = 0; p < 4; ++p)
            #pragma unroll
            for (int i = 0; i < 4; ++i)
              y[ybase + p * 512 + (hh * 4 + i) * 64] =
                  (acc2a[p * 4 + i] + acc2b[p * 4 + i]) + bv[q][p][i];
        }
        BAR_LDS();
      }
    }
}

extern "C" void kernel_launch(void* const* d_in, const int* in_sizes, int n_in,
                              void* d_out, int out_size, void* d_ws, size_t ws_size,
                              hipStream_t stream) {
    const float* x    = (const float*)d_in[0];
    const float* c0   = (const float*)d_in[1];
    const float* c1   = (const float*)d_in[2];
    const float* c2   = (const float*)d_in[3];
    const float* c3   = (const float*)d_in[4];
    const float* bias = (const float*)d_in[5];
    float* yout = (float*)d_out;
    // persistent: 512 blocks (2/CU, LDS-capped), 8 iters x 2 batches each
    tt_kernel<<<512, 256, 0, stream>>>(x, c0, c1, c2, c3, bias, yout);
}